// Round 5
// baseline (2182.589 us; speedup 1.0000x reference)
//
#include <hip/hip_runtime.h>
#include <hip/hip_fp16.h>
#include <stdint.h>

// Problem constants
#define TT   1024
#define NIN  64
#define HH   128
#define GG   384          // 3*H
#define RPB  2            // batch rows per workgroup
#define NWG  256          // 512 rows / 2
#define NTHR 768          // 12 waves; exactly 1 block/CU -> 3 waves/SIMD

// Phase-1 role map (wave-aligned):
//   lid [  0,128)  L0X : layer0 x-dots, G=3 gates, full K=64   (24 uint4 weights)
//   lid [128,320)  L0H : layer0 h-dots, G=4 gates, half K      (32 uint4)
//   lid [320,512)  L1X : layer1 x-dots (input h0), G=4, half K (32 uint4)
//   lid [512,704)  L1H : layer1 h-dots, G=4, half K            (32 uint4)
//   lid [704,768)  stager: x -> xh double buffer
// Phase-2: lid<256 combine layer0, [256,512) combine layer1.

typedef _Float16 half2v __attribute__((ext_vector_type(2)));

__device__ __forceinline__ float fdot2(uint32_t a, uint32_t b, float c) {
    return __builtin_amdgcn_fdot2(__builtin_bit_cast(half2v, a),
                                  __builtin_bit_cast(half2v, b), c, false);
}
__device__ __forceinline__ uint32_t pack2f(float a, float b) {
    half2v v; v[0] = (_Float16)a; v[1] = (_Float16)b;
    return __builtin_bit_cast(uint32_t, v);
}
__device__ __forceinline__ uint4 pack8(const float* p) {
    uint4 r;
    r.x = pack2f(p[0], p[1]); r.y = pack2f(p[2], p[3]);
    r.z = pack2f(p[4], p[5]); r.w = pack2f(p[6], p[7]);
    return r;
}
__device__ __forceinline__ float sigm(float v)     { return 1.f / (1.f + __expf(-v)); }
__device__ __forceinline__ float tanhfast(float v) { return 2.f / (1.f + __expf(-2.f * v)) - 1.f; }

// NOTE: D4 parameter names must NOT be x/y/z/w (member tokens would be substituted).
#define D4(A_, W_, S_) A_ = fdot2(W_.x, S_.x, A_); A_ = fdot2(W_.y, S_.y, A_); \
                       A_ = fdot2(W_.z, S_.z, A_); A_ = fdot2(W_.w, S_.w, A_);

#define PK8(M_, g_) M_(g_,0) M_(g_,1) M_(g_,2) M_(g_,3) M_(g_,4) M_(g_,5) M_(g_,6) M_(g_,7)
#define R8X(M_)     M_(0) M_(1) M_(2) M_(3) M_(4) M_(5) M_(6) M_(7)
#define DWDEF(g_,k_) uint4 W##g_##_##k_;
#define LW(g_,k_)    W##g_##_##k_ = pack8(wp + (g_)*ws + (k_)*8);
// one state uint4 (8 halves) applied to gates' accumulators, both rows
#define DG(g_,k_) D4(a##g_##_0, W##g_##_##k_, s0_) D4(a##g_##_1, W##g_##_##k_, s1_)
#define SK4(k_) { uint4 s0_ = pb0[k_], s1_ = pb1[k_]; DG(0,k_) DG(1,k_) DG(2,k_) DG(3,k_) }
#define SK3(k_) { uint4 s0_ = pb0[k_], s1_ = pb1[k_]; DG(0,k_) DG(1,k_) DG(2,k_) }

__global__ __launch_bounds__(NTHR)
__attribute__((amdgpu_waves_per_eu(3, 3)))   // pin occupancy target: 3 waves/EU -> 168-VGPR budget, no spill
void gru_fused(
    const float* __restrict__ x,
    const float* __restrict__ Wih0, const float* __restrict__ Whh0,
    const float* __restrict__ bih0, const float* __restrict__ bhh0,
    const float* __restrict__ Wih1, const float* __restrict__ Whh1,
    const float* __restrict__ bih1, const float* __restrict__ bhh1,
    const float* __restrict__ fc1w, const float* __restrict__ fc1b,
    const float* __restrict__ fc2w, const float* __restrict__ fc2b,
    float* __restrict__ out)
{
    __shared__ __align__(16) uint32_t xh[2][RPB][NIN / 2];   // x_t fp16x2, double-buffered
    __shared__ __align__(16) uint32_t h0h[RPB][HH / 2];      // layer0 h fp16x2
    __shared__ __align__(16) uint32_t h1h[RPB][HH / 2];      // layer1 h fp16x2
    __shared__ float h0f[RPB][HH];                           // layer0 h fp32
    __shared__ float h1f[RPB][HH];                           // layer1 h fp32
    __shared__ float pX0[RPB][GG];                           // layer0 x-part (full)
    // Partial pre-acts, [row][gate-quad][K-half][4]: kh fastest -> conflict-free
    // float4 writes (consecutive lanes hit consecutive 16B).
    __shared__ __align__(16) float pH0q[RPB][96][2][4];
    __shared__ __align__(16) float pX1q[RPB][96][2][4];
    __shared__ __align__(16) float pH1q[RPB][96][2][4];

    const int lid  = threadIdx.x;
    const int row0 = blockIdx.x * RPB;

    // Named register-resident packed weights (max 32 uint4 = 128 VGPR).
    PK8(DWDEF,0) PK8(DWDEF,1) PK8(DWDEF,2) PK8(DWDEF,3)
    float b0 = 0.f, b1 = 0.f, b2 = 0.f, b3 = 0.f;   // acc init (bias in kh=0 only)
    int gq_ = 0, kh_ = 0;
    const uint4 *pbA0 = nullptr, *pbA1 = nullptr;    // invariant state base ptrs (h-roles)
    float2 xr2 = {0.f, 0.f};                         // stager prefetch

    if (lid < 128) {                       // L0X: gates 3t..3t+2, K=64 full
        const int t = lid;
        const float* wp = Wih0 + (3 * t) * NIN; const int ws = NIN;
        PK8(LW,0) PK8(LW,1) PK8(LW,2)
        b0 = bih0[3 * t]; b1 = bih0[3 * t + 1]; b2 = bih0[3 * t + 2];
    } else if (lid < 320) {                // L0H: gates 4gq..4gq+3, K-half kh
        const int t = lid - 128; gq_ = t >> 1; kh_ = t & 1;
        const float* wp = Whh0 + (4 * gq_) * HH + kh_ * 64; const int ws = HH;
        PK8(LW,0) PK8(LW,1) PK8(LW,2) PK8(LW,3)
        if (!kh_) { b0 = bhh0[4*gq_]; b1 = bhh0[4*gq_+1]; b2 = bhh0[4*gq_+2]; b3 = bhh0[4*gq_+3]; }
        pbA0 = (const uint4*)&h0h[0][0] + kh_ * 8;
        pbA1 = (const uint4*)&h0h[1][0] + kh_ * 8;
    } else if (lid < 512) {                // L1X: input is h0
        const int t = lid - 320; gq_ = t >> 1; kh_ = t & 1;
        const float* wp = Wih1 + (4 * gq_) * HH + kh_ * 64; const int ws = HH;
        PK8(LW,0) PK8(LW,1) PK8(LW,2) PK8(LW,3)
        if (!kh_) { b0 = bih1[4*gq_]; b1 = bih1[4*gq_+1]; b2 = bih1[4*gq_+2]; b3 = bih1[4*gq_+3]; }
        pbA0 = (const uint4*)&h0h[0][0] + kh_ * 8;
        pbA1 = (const uint4*)&h0h[1][0] + kh_ * 8;
    } else if (lid < 704) {                // L1H
        const int t = lid - 512; gq_ = t >> 1; kh_ = t & 1;
        const float* wp = Whh1 + (4 * gq_) * HH + kh_ * 64; const int ws = HH;
        PK8(LW,0) PK8(LW,1) PK8(LW,2) PK8(LW,3)
        if (!kh_) { b0 = bhh1[4*gq_]; b1 = bhh1[4*gq_+1]; b2 = bhh1[4*gq_+2]; b3 = bhh1[4*gq_+3]; }
        pbA0 = (const uint4*)&h1h[0][0] + kh_ * 8;
        pbA1 = (const uint4*)&h1h[1][0] + kh_ * 8;
    } else {                               // stager: x_0 into xh[0], prefetch x_1
        const int idx = lid - 704, r = idx >> 5, c = idx & 31;
        const float* xp = x + (size_t)(row0 + r) * TT * NIN + 2 * c;
        xh[0][r][c] = pack2f(xp[0], xp[1]);
        xr2 = *(const float2*)(xp + NIN);
    }

    // Zero-init states (any threads, pre-barrier).
    if (lid < 128) {
        int r = lid >> 6, c = lid & 63;
        h0h[r][c] = 0u; h1h[r][c] = 0u;
    }
    if (lid < 256) {
        int r = lid >> 7, j = lid & 127;
        h0f[r][j] = 0.f; h1f[r][j] = 0.f;
    }
    __syncthreads();

    // Iteration i: layer0 computes step i (i<TT); layer1 computes step i-1 (i>=1).
    for (int i = 0; i <= TT; ++i) {
        // ---------------- phase 1: dots (+ x staging into the other buffer) ----
        if (lid < 128) {
            if (i < TT) {
                const uint4* pb0 = (const uint4*)&xh[i & 1][0][0];
                const uint4* pb1 = (const uint4*)&xh[i & 1][1][0];
                float a0_0 = b0, a0_1 = b0, a1_0 = b1, a1_1 = b1, a2_0 = b2, a2_1 = b2;
                R8X(SK3)
                const int g0 = 3 * lid;
                pX0[0][g0] = a0_0; pX0[0][g0+1] = a1_0; pX0[0][g0+2] = a2_0;
                pX0[1][g0] = a0_1; pX0[1][g0+1] = a1_1; pX0[1][g0+2] = a2_1;
            }
        } else if (lid < 320) {
            if (i < TT) {
                const uint4 *pb0 = pbA0, *pb1 = pbA1;
                float a0_0=b0,a0_1=b0,a1_0=b1,a1_1=b1,a2_0=b2,a2_1=b2,a3_0=b3,a3_1=b3;
                R8X(SK4)
                float4 v0 = {a0_0, a1_0, a2_0, a3_0};
                float4 v1 = {a0_1, a1_1, a2_1, a3_1};
                *(float4*)&pH0q[0][gq_][kh_][0] = v0;
                *(float4*)&pH0q[1][gq_][kh_][0] = v1;
            }
        } else if (lid < 512) {
            if (i >= 1) {
                const uint4 *pb0 = pbA0, *pb1 = pbA1;
                float a0_0=b0,a0_1=b0,a1_0=b1,a1_1=b1,a2_0=b2,a2_1=b2,a3_0=b3,a3_1=b3;
                R8X(SK4)
                float4 v0 = {a0_0, a1_0, a2_0, a3_0};
                float4 v1 = {a0_1, a1_1, a2_1, a3_1};
                *(float4*)&pX1q[0][gq_][kh_][0] = v0;
                *(float4*)&pX1q[1][gq_][kh_][0] = v1;
            }
        } else if (lid < 704) {
            if (i >= 1) {
                const uint4 *pb0 = pbA0, *pb1 = pbA1;
                float a0_0=b0,a0_1=b0,a1_0=b1,a1_1=b1,a2_0=b2,a2_1=b2,a3_0=b3,a3_1=b3;
                R8X(SK4)
                float4 v0 = {a0_0, a1_0, a2_0, a3_0};
                float4 v1 = {a0_1, a1_1, a2_1, a3_1};
                *(float4*)&pH1q[0][gq_][kh_][0] = v0;
                *(float4*)&pH1q[1][gq_][kh_][0] = v1;
            }
        } else {
            // stager: write x_{i+1} into the buffer phase-1 readers are NOT using.
            const int idx = lid - 704, r = idx >> 5, c = idx & 31;
            if (i + 1 < TT) xh[(i + 1) & 1][r][c] = pack2f(xr2.x, xr2.y);
            if (i + 2 < TT)
                xr2 = *(const float2*)(x + (size_t)(row0 + r) * TT * NIN
                                         + (size_t)(i + 2) * NIN + 2 * c);
        }
        __syncthreads();

        // ---------------- phase 2: gate combine ----------------
        if (lid < 256) {                       // layer0
            if (i < TT) {
                const int r = lid >> 7, j = lid & 127;
                const int q = j >> 2, m = j & 3;
                float xr_ = pX0[r][j], xz_ = pX0[r][HH + j], xn_ = pX0[r][2*HH + j];
                float hr_ = pH0q[r][q][0][m]      + pH0q[r][q][1][m];
                float hz_ = pH0q[r][32 + q][0][m] + pH0q[r][32 + q][1][m];
                float hn_ = pH0q[r][64 + q][0][m] + pH0q[r][64 + q][1][m];
                float rg = sigm(xr_ + hr_);
                float zg = sigm(xz_ + hz_);
                float ng = tanhfast(fmaf(rg, hn_, xn_));
                float hnew = fmaf(zg, h0f[r][j] - ng, ng);     // n + z*(h-n)
                h0f[r][j] = hnew;
                ((__half*)&h0h[r][0])[j] = __float2half(hnew);
            }
        } else if (lid < 512) {                // layer1
            if (i >= 1) {
                const int t = lid - 256, r = t >> 7, j = t & 127;
                const int q = j >> 2, m = j & 3;
                float xr_ = pX1q[r][q][0][m]      + pX1q[r][q][1][m];
                float xz_ = pX1q[r][32 + q][0][m] + pX1q[r][32 + q][1][m];
                float xn_ = pX1q[r][64 + q][0][m] + pX1q[r][64 + q][1][m];
                float hr_ = pH1q[r][q][0][m]      + pH1q[r][q][1][m];
                float hz_ = pH1q[r][32 + q][0][m] + pH1q[r][32 + q][1][m];
                float hn_ = pH1q[r][64 + q][0][m] + pH1q[r][64 + q][1][m];
                float rg = sigm(xr_ + hr_);
                float zg = sigm(xz_ + hz_);
                float ng = tanhfast(fmaf(rg, hn_, xn_));
                float hnew = fmaf(zg, h1f[r][j] - ng, ng);
                h1f[r][j] = hnew;
                ((__half*)&h1h[r][0])[j] = __float2half(hnew);
            }
        }
        __syncthreads();
    }

    // ---------------- FC head: y = fc2 . relu(fc1 @ h2 + b1) + b2 ----------------
    float yv = 0.f;
    if (lid < 256) {
        const int r = lid >> 7, j = lid & 127;
        const float* fr = fc1w + j * HH;
        float acc = fc1b[j];
        #pragma unroll 8
        for (int k = 0; k < HH; ++k) acc = fmaf(fr[k], h1f[r][k], acc);
        yv = fmaxf(acc, 0.f) * fc2w[j];
        #pragma unroll
        for (int m = 1; m < 64; m <<= 1) yv += __shfl_xor(yv, m, 64);
    }
    __syncthreads();
    if (lid < 256 && (lid & 63) == 0) pX0[0][lid >> 6] = yv;   // 4 wave sums
    __syncthreads();
    if (lid < RPB) out[row0 + lid] = pX0[0][2 * lid] + pX0[0][2 * lid + 1] + fc2b[0];
}

extern "C" void kernel_launch(void* const* d_in, const int* in_sizes, int n_in,
                              void* d_out, int out_size, void* d_ws, size_t ws_size,
                              hipStream_t stream) {
    const float* x    = (const float*)d_in[0];
    const float* Wih0 = (const float*)d_in[1];
    const float* Whh0 = (const float*)d_in[2];
    const float* bih0 = (const float*)d_in[3];
    const float* bhh0 = (const float*)d_in[4];
    const float* Wih1 = (const float*)d_in[5];
    const float* Whh1 = (const float*)d_in[6];
    const float* bih1 = (const float*)d_in[7];
    const float* bhh1 = (const float*)d_in[8];
    const float* fc1w = (const float*)d_in[9];
    const float* fc1b = (const float*)d_in[10];
    const float* fc2w = (const float*)d_in[11];
    const float* fc2b = (const float*)d_in[12];

    gru_fused<<<dim3(NWG), dim3(NTHR), 0, stream>>>(
        x, Wih0, Whh0, bih0, bhh0, Wih1, Whh1, bih1, bhh1,
        fc1w, fc1b, fc2w, fc2b, (float*)d_out);
}

// Round 6
// 2116.128 us; speedup vs baseline: 1.0314x; 1.0314x over previous
//
#include <hip/hip_runtime.h>
#include <hip/hip_fp16.h>
#include <stdint.h>

// Problem constants
#define TT   1024
#define NIN  64
#define HH   128
#define GG   384          // 3*H
#define RPB  2            // batch rows per workgroup
#define NWG  256          // 512 rows / 2
#define NTHR 768          // 12 waves; 1 block/CU -> 3 waves/SIMD

// Packed-weight workspace layout (uint4 = 8 fp16):
//   Wih0: rows of 8 uint4,  base 0      (384*8  = 3072)
//   Whh0: rows of 16 uint4, base 3072   (384*16 = 6144)
//   Wih1: rows of 16 uint4, base 9216
//   Whh1: rows of 16 uint4, base 15360  (ends 21504 uint4 = 344 KB)
#define WB_IH0 0
#define WB_HH0 3072
#define WB_IH1 9216
#define WB_HH1 15360

typedef _Float16 half2v __attribute__((ext_vector_type(2)));

__device__ __forceinline__ float fdot2(uint32_t a, uint32_t b, float c) {
    return __builtin_amdgcn_fdot2(__builtin_bit_cast(half2v, a),
                                  __builtin_bit_cast(half2v, b), c, false);
}
__device__ __forceinline__ uint32_t pack2f(float a, float b) {
    half2v v; v[0] = (_Float16)a; v[1] = (_Float16)b;
    return __builtin_bit_cast(uint32_t, v);
}
__device__ __forceinline__ float sigm(float v)     { return 1.f / (1.f + __expf(-v)); }
__device__ __forceinline__ float tanhfast(float v) { return 2.f / (1.f + __expf(-2.f * v)) - 1.f; }

// NOTE: D4 parameter names must NOT be x/y/z/w (member tokens would be substituted).
#define D4(A_, W_, S_) A_ = fdot2(W_.x, S_.x, A_); A_ = fdot2(W_.y, S_.y, A_); \
                       A_ = fdot2(W_.z, S_.z, A_); A_ = fdot2(W_.w, S_.w, A_);

#define PK8(M_, g_) M_(g_,0) M_(g_,1) M_(g_,2) M_(g_,3) M_(g_,4) M_(g_,5) M_(g_,6) M_(g_,7)
#define R8X(M_)     M_(0) M_(1) M_(2) M_(3) M_(4) M_(5) M_(6) M_(7)
#define DWDEF(g_,k_) uint4 W##g_##_##k_;
// Direct b128 load of pre-packed fp16 weights: dest reg IS the permanent home.
#define LW(g_,k_)    W##g_##_##k_ = wp[(g_)*wst + (k_)];
// one state uint4 (8 halves) applied to gates' accumulators, both rows
#define DG(g_,k_) D4(a##g_##_0, W##g_##_##k_, s0_) D4(a##g_##_1, W##g_##_##k_, s1_)
#define SK4(k_) { uint4 s0_ = pb0[k_], s1_ = pb1[k_]; DG(0,k_) DG(1,k_) DG(2,k_) DG(3,k_) }
#define SK3(k_) { uint4 s0_ = pb0[k_], s1_ = pb1[k_]; DG(0,k_) DG(1,k_) DG(2,k_) }

// ---------------- pre-kernel: convert f32 weights -> packed fp16 in ws ----------
__global__ __launch_bounds__(256) void pack_weights(
    const float* __restrict__ Wih0, const float* __restrict__ Whh0,
    const float* __restrict__ Wih1, const float* __restrict__ Whh1,
    uint32_t* __restrict__ ws)
{
    const int i = blockIdx.x * 256 + threadIdx.x;   // pair index, grid covers 86016 exactly
    const int P0 = 384 * 64 / 2, P1 = 384 * 128 / 2;
    const float* src; int off;
    if (i < P0)               { src = Wih0; off = i; }
    else if (i < P0 + P1)     { src = Whh0; off = i - P0; }
    else if (i < P0 + 2 * P1) { src = Wih1; off = i - P0 - P1; }
    else                      { src = Whh1; off = i - P0 - 2 * P1; }
    const float2 v = *(const float2*)(src + 2 * off);
    ws[i] = pack2f(v.x, v.y);
}

// ---------------- main fused GRU kernel ----------------
__global__ __launch_bounds__(NTHR)
__attribute__((amdgpu_waves_per_eu(3, 3)))
void gru_fused(
    const float* __restrict__ x,
    const uint32_t* __restrict__ wsw,
    const float* __restrict__ bih0, const float* __restrict__ bhh0,
    const float* __restrict__ bih1, const float* __restrict__ bhh1,
    const float* __restrict__ fc1w, const float* __restrict__ fc1b,
    const float* __restrict__ fc2w, const float* __restrict__ fc2b,
    float* __restrict__ out)
{
    __shared__ __align__(16) uint32_t xh[2][RPB][NIN / 2];   // x_t fp16x2, double-buffered
    __shared__ __align__(16) uint32_t h0h[RPB][HH / 2];      // layer0 h fp16x2
    __shared__ __align__(16) uint32_t h1h[RPB][HH / 2];      // layer1 h fp16x2
    __shared__ float h0f[RPB][HH];                           // layer0 h fp32
    __shared__ float h1f[RPB][HH];                           // layer1 h fp32
    __shared__ float pX0[RPB][GG];                           // layer0 x-part (full)
    // Partial pre-acts, [row][gate-quad][K-half][4]
    __shared__ __align__(16) float pH0q[RPB][96][2][4];
    __shared__ __align__(16) float pX1q[RPB][96][2][4];
    __shared__ __align__(16) float pH1q[RPB][96][2][4];

    const int lid  = threadIdx.x;
    const int row0 = blockIdx.x * RPB;

    // Named register-resident packed weights (max 32 uint4 = 128 VGPR).
    PK8(DWDEF,0) PK8(DWDEF,1) PK8(DWDEF,2) PK8(DWDEF,3)
    float b0 = 0.f, b1 = 0.f, b2 = 0.f, b3 = 0.f;   // acc init (bias in kh=0 only)
    int gq_ = 0, kh_ = 0;
    const uint4 *pbA0 = nullptr, *pbA1 = nullptr;    // invariant state base ptrs (h-roles)
    float2 xr2 = {0.f, 0.f};                         // stager prefetch

    const uint4* wv = (const uint4*)wsw;

    if (lid < 128) {                       // L0X: gates 3t..3t+2, K=64 full
        const int t = lid;
        const uint4* wp = wv + WB_IH0 + (3 * t) * 8; const int wst = 8;
        PK8(LW,0) PK8(LW,1) PK8(LW,2)
        b0 = bih0[3 * t]; b1 = bih0[3 * t + 1]; b2 = bih0[3 * t + 2];
    } else if (lid < 320) {                // L0H: gates 4gq..4gq+3, K-half kh
        const int t = lid - 128; gq_ = t >> 1; kh_ = t & 1;
        const uint4* wp = wv + WB_HH0 + (4 * gq_) * 16 + kh_ * 8; const int wst = 16;
        PK8(LW,0) PK8(LW,1) PK8(LW,2) PK8(LW,3)
        if (!kh_) { b0 = bhh0[4*gq_]; b1 = bhh0[4*gq_+1]; b2 = bhh0[4*gq_+2]; b3 = bhh0[4*gq_+3]; }
        pbA0 = (const uint4*)&h0h[0][0] + kh_ * 8;
        pbA1 = (const uint4*)&h0h[1][0] + kh_ * 8;
    } else if (lid < 512) {                // L1X: input is h0
        const int t = lid - 320; gq_ = t >> 1; kh_ = t & 1;
        const uint4* wp = wv + WB_IH1 + (4 * gq_) * 16 + kh_ * 8; const int wst = 16;
        PK8(LW,0) PK8(LW,1) PK8(LW,2) PK8(LW,3)
        if (!kh_) { b0 = bih1[4*gq_]; b1 = bih1[4*gq_+1]; b2 = bih1[4*gq_+2]; b3 = bih1[4*gq_+3]; }
        pbA0 = (const uint4*)&h0h[0][0] + kh_ * 8;
        pbA1 = (const uint4*)&h0h[1][0] + kh_ * 8;
    } else if (lid < 704) {                // L1H
        const int t = lid - 512; gq_ = t >> 1; kh_ = t & 1;
        const uint4* wp = wv + WB_HH1 + (4 * gq_) * 16 + kh_ * 8; const int wst = 16;
        PK8(LW,0) PK8(LW,1) PK8(LW,2) PK8(LW,3)
        if (!kh_) { b0 = bhh1[4*gq_]; b1 = bhh1[4*gq_+1]; b2 = bhh1[4*gq_+2]; b3 = bhh1[4*gq_+3]; }
        pbA0 = (const uint4*)&h1h[0][0] + kh_ * 8;
        pbA1 = (const uint4*)&h1h[1][0] + kh_ * 8;
    } else {                               // stager: x_0 into xh[0], prefetch x_1
        const int idx = lid - 704, r = idx >> 5, c = idx & 31;
        const float* xp = x + (size_t)(row0 + r) * TT * NIN + 2 * c;
        xh[0][r][c] = pack2f(xp[0], xp[1]);
        xr2 = *(const float2*)(xp + NIN);
    }

    // Zero-init states (any threads, pre-barrier).
    if (lid < 128) {
        int r = lid >> 6, c = lid & 63;
        h0h[r][c] = 0u; h1h[r][c] = 0u;
    }
    if (lid < 256) {
        int r = lid >> 7, j = lid & 127;
        h0f[r][j] = 0.f; h1f[r][j] = 0.f;
    }
    __syncthreads();

    // Iteration i: layer0 computes step i (i<TT); layer1 computes step i-1 (i>=1).
    for (int i = 0; i <= TT; ++i) {
        // ---------------- phase 1: dots (+ x staging into the other buffer) ----
        if (lid < 128) {
            if (i < TT) {
                const uint4* pb0 = (const uint4*)&xh[i & 1][0][0];
                const uint4* pb1 = (const uint4*)&xh[i & 1][1][0];
                float a0_0 = b0, a0_1 = b0, a1_0 = b1, a1_1 = b1, a2_0 = b2, a2_1 = b2;
                R8X(SK3)
                const int g0 = 3 * lid;
                pX0[0][g0] = a0_0; pX0[0][g0+1] = a1_0; pX0[0][g0+2] = a2_0;
                pX0[1][g0] = a0_1; pX0[1][g0+1] = a1_1; pX0[1][g0+2] = a2_1;
            }
        } else if (lid < 320) {
            if (i < TT) {
                const uint4 *pb0 = pbA0, *pb1 = pbA1;
                float a0_0=b0,a0_1=b0,a1_0=b1,a1_1=b1,a2_0=b2,a2_1=b2,a3_0=b3,a3_1=b3;
                R8X(SK4)
                float4 v0 = {a0_0, a1_0, a2_0, a3_0};
                float4 v1 = {a0_1, a1_1, a2_1, a3_1};
                *(float4*)&pH0q[0][gq_][kh_][0] = v0;
                *(float4*)&pH0q[1][gq_][kh_][0] = v1;
            }
        } else if (lid < 512) {
            if (i >= 1) {
                const uint4 *pb0 = pbA0, *pb1 = pbA1;
                float a0_0=b0,a0_1=b0,a1_0=b1,a1_1=b1,a2_0=b2,a2_1=b2,a3_0=b3,a3_1=b3;
                R8X(SK4)
                float4 v0 = {a0_0, a1_0, a2_0, a3_0};
                float4 v1 = {a0_1, a1_1, a2_1, a3_1};
                *(float4*)&pX1q[0][gq_][kh_][0] = v0;
                *(float4*)&pX1q[1][gq_][kh_][0] = v1;
            }
        } else if (lid < 704) {
            if (i >= 1) {
                const uint4 *pb0 = pbA0, *pb1 = pbA1;
                float a0_0=b0,a0_1=b0,a1_0=b1,a1_1=b1,a2_0=b2,a2_1=b2,a3_0=b3,a3_1=b3;
                R8X(SK4)
                float4 v0 = {a0_0, a1_0, a2_0, a3_0};
                float4 v1 = {a0_1, a1_1, a2_1, a3_1};
                *(float4*)&pH1q[0][gq_][kh_][0] = v0;
                *(float4*)&pH1q[1][gq_][kh_][0] = v1;
            }
        } else {
            // stager: write x_{i+1} into the buffer phase-1 readers are NOT using.
            const int idx = lid - 704, r = idx >> 5, c = idx & 31;
            if (i + 1 < TT) xh[(i + 1) & 1][r][c] = pack2f(xr2.x, xr2.y);
            if (i + 2 < TT)
                xr2 = *(const float2*)(x + (size_t)(row0 + r) * TT * NIN
                                         + (size_t)(i + 2) * NIN + 2 * c);
        }
        __syncthreads();

        // ---------------- phase 2: gate combine ----------------
        if (lid < 256) {                       // layer0
            if (i < TT) {
                const int r = lid >> 7, j = lid & 127;
                const int q = j >> 2, m = j & 3;
                float xr_ = pX0[r][j], xz_ = pX0[r][HH + j], xn_ = pX0[r][2*HH + j];
                float hr_ = pH0q[r][q][0][m]      + pH0q[r][q][1][m];
                float hz_ = pH0q[r][32 + q][0][m] + pH0q[r][32 + q][1][m];
                float hn_ = pH0q[r][64 + q][0][m] + pH0q[r][64 + q][1][m];
                float rg = sigm(xr_ + hr_);
                float zg = sigm(xz_ + hz_);
                float ng = tanhfast(fmaf(rg, hn_, xn_));
                float hnew = fmaf(zg, h0f[r][j] - ng, ng);     // n + z*(h-n)
                h0f[r][j] = hnew;
                ((__half*)&h0h[r][0])[j] = __float2half(hnew);
            }
        } else if (lid < 512) {                // layer1
            if (i >= 1) {
                const int t = lid - 256, r = t >> 7, j = t & 127;
                const int q = j >> 2, m = j & 3;
                float xr_ = pX1q[r][q][0][m]      + pX1q[r][q][1][m];
                float xz_ = pX1q[r][32 + q][0][m] + pX1q[r][32 + q][1][m];
                float xn_ = pX1q[r][64 + q][0][m] + pX1q[r][64 + q][1][m];
                float hr_ = pH1q[r][q][0][m]      + pH1q[r][q][1][m];
                float hz_ = pH1q[r][32 + q][0][m] + pH1q[r][32 + q][1][m];
                float hn_ = pH1q[r][64 + q][0][m] + pH1q[r][64 + q][1][m];
                float rg = sigm(xr_ + hr_);
                float zg = sigm(xz_ + hz_);
                float ng = tanhfast(fmaf(rg, hn_, xn_));
                float hnew = fmaf(zg, h1f[r][j] - ng, ng);
                h1f[r][j] = hnew;
                ((__half*)&h1h[r][0])[j] = __float2half(hnew);
            }
        }
        __syncthreads();
    }

    // ---------------- FC head: y = fc2 . relu(fc1 @ h2 + b1) + b2 ----------------
    float yv = 0.f;
    if (lid < 256) {
        const int r = lid >> 7, j = lid & 127;
        const float* fr = fc1w + j * HH;
        float acc = fc1b[j];
        #pragma unroll 8
        for (int k = 0; k < HH; ++k) acc = fmaf(fr[k], h1f[r][k], acc);
        yv = fmaxf(acc, 0.f) * fc2w[j];
        #pragma unroll
        for (int m = 1; m < 64; m <<= 1) yv += __shfl_xor(yv, m, 64);
    }
    __syncthreads();
    if (lid < 256 && (lid & 63) == 0) pX0[0][lid >> 6] = yv;   // 4 wave sums
    __syncthreads();
    if (lid < RPB) out[row0 + lid] = pX0[0][2 * lid] + pX0[0][2 * lid + 1] + fc2b[0];
}

extern "C" void kernel_launch(void* const* d_in, const int* in_sizes, int n_in,
                              void* d_out, int out_size, void* d_ws, size_t ws_size,
                              hipStream_t stream) {
    const float* x    = (const float*)d_in[0];
    const float* Wih0 = (const float*)d_in[1];
    const float* Whh0 = (const float*)d_in[2];
    const float* bih0 = (const float*)d_in[3];
    const float* bhh0 = (const float*)d_in[4];
    const float* Wih1 = (const float*)d_in[5];
    const float* Whh1 = (const float*)d_in[6];
    const float* bih1 = (const float*)d_in[7];
    const float* bhh1 = (const float*)d_in[8];
    const float* fc1w = (const float*)d_in[9];
    const float* fc1b = (const float*)d_in[10];
    const float* fc2w = (const float*)d_in[11];
    const float* fc2b = (const float*)d_in[12];

    uint32_t* ws = (uint32_t*)d_ws;   // 344 KB of packed fp16 weights

    pack_weights<<<dim3(86016 / 256), dim3(256), 0, stream>>>(Wih0, Whh0, Wih1, Whh1, ws);
    gru_fused<<<dim3(NWG), dim3(NTHR), 0, stream>>>(
        x, ws, bih0, bhh0, bih1, bhh1,
        fc1w, fc1b, fc2w, fc2b, (float*)d_out);
}